// Round 7
// baseline (181.698 us; speedup 1.0000x reference)
//
#include <hip/hip_runtime.h>
#include <hip/hip_fp16.h>
#include <math.h>

#define N_NODES 12000
#define C 128
#define NEDGE 192000
#define BW 384  // u32 words per LDS dedup bitset (12288 bits >= 12000)

// acc_lo += (float)f16_lo(u); acc_hi += (float)f16_hi(u)  -- one VOP3P each
__device__ __forceinline__ void fmix2(float& lo, float& hi, unsigned u, float one) {
    asm("v_fma_mix_f32 %0, %2, %3, %0 op_sel:[0,0,0] op_sel_hi:[1,0,0]\n\t"
        "v_fma_mix_f32 %1, %2, %3, %1 op_sel:[1,0,0] op_sel_hi:[1,0,0]"
        : "+v"(lo), "+v"(hi)
        : "v"(u), "v"(one));
}

#define ACCM(p, u)                                           \
    fmix2(p##0, p##1, u.x, one); fmix2(p##2, p##3, u.y, one); \
    fmix2(p##4, p##5, u.z, one); fmix2(p##6, p##7, u.w, one)

#define RED2(x) x += __shfl_xor(x, 16); x += __shfl_xor(x, 32)

// ---- fused: x (fp32) -> f16 packed pairs  +  out-degree histogram ----
__global__ void prep(const float* __restrict__ x, unsigned* __restrict__ xbu,
                     const int* __restrict__ ei, int* __restrict__ deg) {
    int g = blockIdx.x * blockDim.x + threadIdx.x;
    if (g < N_NODES * C / 2) {
        unsigned pa = __half_as_ushort(__float2half(x[2 * g]));
        unsigned pb = __half_as_ushort(__float2half(x[2 * g + 1]));
        xbu[g] = pa | (pb << 16);
    }
    if (g < NEDGE) atomicAdd(&deg[ei[g]], 1);
}

// ---- exclusive scan of degrees -> CSR offsets (single 1024-thread block) ----
__global__ __launch_bounds__(1024) void scan_offsets(const int* __restrict__ deg,
                                                     int* __restrict__ off) {
    __shared__ int wsum[16];
    const int t = threadIdx.x;
    const int lane = t & 63, wv = t >> 6;
    const int PER = 12;  // 1024*12 = 12288 >= 12000
    const int lo = t * PER;
    int local[PER];
    int sum = 0;
#pragma unroll
    for (int k = 0; k < PER; ++k) {
        int i = lo + k;
        int d = (i < N_NODES) ? deg[i] : 0;
        local[k] = sum;
        sum += d;
    }
    int p = sum;
    for (int d = 1; d < 64; d <<= 1) {
        int u = __shfl_up(p, d);
        if (lane >= d) p += u;
    }
    if (lane == 63) wsum[wv] = p;
    __syncthreads();
    int wbase = 0;
    for (int k = 0; k < wv; ++k) wbase += wsum[k];
    const int tbase = wbase + p - sum;
#pragma unroll
    for (int k = 0; k < PER; ++k) {
        int i = lo + k;
        if (i < N_NODES) off[i] = tbase + local[k];
    }
    if (t == 0) off[N_NODES] = NEDGE;
}

// ---- fill CSR columns (order within row irrelevant; duplicates kept) ----
__global__ void fill_csr(const int* __restrict__ ei, const int* __restrict__ off,
                         int* __restrict__ cur, int* __restrict__ col) {
    int e = blockIdx.x * blockDim.x + threadIdx.x;
    if (e >= NEDGE) return;
    int s = ei[e];
    int t = ei[NEDGE + e];
    int pos = atomicAdd(&cur[s], 1);
    col[off[s] + pos] = t;
}

// ---- fused: agg1 (f16 CSR gather) + flattened 2-hop union + list gather ----
__global__ __launch_bounds__(512) void twohop_fused(const int* __restrict__ off,
                                                    const int* __restrict__ col,
                                                    const unsigned* __restrict__ xb,
                                                    float* __restrict__ agg1,
                                                    float* __restrict__ agg2) {
    __shared__ unsigned acc[BW];           // 1.5 KB dedup bitset
    __shared__ int sjb[64];
    __shared__ int spos[64];
    __shared__ int stot;
    __shared__ int wtotA[6];
    __shared__ unsigned short lst[12288];  // 24 KB; full bitset capacity, one pass
    __shared__ float red[8][256];          // 8 KB
    const int i = blockIdx.x;
    const int tid = threadIdx.x;
    const int lane = tid & 63;
    const int wv = tid >> 6;
    const int grp = tid >> 4, l16 = tid & 15;  // 32 groups of 16 lanes
    const int rowbeg = off[i], rowend = off[i + 1];
    const uint4* xb4 = (const uint4*)xb;
    const float one = 1.0f;

    if (tid < BW) acc[tid] = 0u;
    __syncthreads();  // acc ready for atomics

    // ---- 2-hop union, flattened per 64-neighbor chunk ----
    for (int base = rowbeg; base < rowend; base += 64) {
        int d = rowend - base;
        if (d > 64) d = 64;
        if (tid < 64) {
            int len = 0;
            if (tid < d) {
                int j = col[base + tid];
                int jb = off[j];
                len = off[j + 1] - jb;
                sjb[tid] = jb;
            }
            int p = len;
            for (int dd = 1; dd < 64; dd <<= 1) {
                int u = __shfl_up(p, dd);
                if (lane >= dd) p += u;
            }
            spos[tid] = p - len;  // exclusive
            if (tid == 63) stot = p;
        }
        __syncthreads();
        const int total = stot;
        for (int q = tid; q < total; q += 512) {
            int lo = 0, hi = d - 1;  // largest k with spos[k] <= q
            while (lo < hi) {
                int mid = (lo + hi + 1) >> 1;
                if (spos[mid] <= q) lo = mid; else hi = mid - 1;
            }
            int t = col[sjb[lo] + (q - spos[lo])];
            atomicOr(&acc[t >> 5], 1u << (t & 31));
        }
        __syncthreads();
    }
    if (tid == 0) acc[i >> 5] &= ~(1u << (i & 31));  // zero diagonal

    // ---- agg1: f16 counted gather over own row (multiplicity kept), 2x unrolled ----
    float b0 = 0, b1 = 0, b2 = 0, b3 = 0, b4 = 0, b5 = 0, b6 = 0, b7 = 0;
    {
        int idx = rowbeg + grp;
        for (; idx + 32 < rowend; idx += 64) {
            int k0 = col[idx], k1 = col[idx + 32];
            uint4 u0 = xb4[(unsigned)((k0 << 4) | l16)];
            uint4 u1 = xb4[(unsigned)((k1 << 4) | l16)];
            ACCM(b, u0);
            ACCM(b, u1);
        }
        if (idx < rowend) {
            int k0 = col[idx];
            uint4 u0 = xb4[(unsigned)((k0 << 4) | l16)];
            ACCM(b, u0);
        }
    }

    // ---- enumerate all 384 words in one pass (prefix-scan reservation) ----
    __syncthreads();  // diag clear visible
    unsigned v = 0;
    int n = 0, p = 0;
    if (tid < 384) {
        v = acc[tid];
        n = __popc(v);
        p = n;
        for (int dd = 1; dd < 64; dd <<= 1) {
            int u = __shfl_up(p, dd);
            if (lane >= dd) p += u;
        }
        if (lane == 63) wtotA[wv] = p;
    }
    __syncthreads();
    int tot = 0;
#pragma unroll
    for (int k = 0; k < 6; ++k) tot += wtotA[k];
    if (tid < 384 && v) {
        int basew = 0;
        for (int k = 0; k < wv; ++k) basew += wtotA[k];
        int o = basew + p - n;
        int wbase = tid << 5;
        while (v) {
            int b = __ffs(v) - 1;
            v &= v - 1;
            lst[o++] = (unsigned short)(wbase + b);
        }
    }
    __syncthreads();

    // ---- agg2: counted gather over lst, 4x unrolled, 32 groups ----
    float a0 = 0, a1 = 0, a2 = 0, a3 = 0, a4 = 0, a5 = 0, a6 = 0, a7 = 0;
    {
        int q = grp;
        for (; q + 96 < tot; q += 128) {
            int k0 = lst[q], k1 = lst[q + 32], k2 = lst[q + 64], k3 = lst[q + 96];
            uint4 u0 = xb4[(unsigned)((k0 << 4) | l16)];
            uint4 u1 = xb4[(unsigned)((k1 << 4) | l16)];
            uint4 u2 = xb4[(unsigned)((k2 << 4) | l16)];
            uint4 u3 = xb4[(unsigned)((k3 << 4) | l16)];
            ACCM(a, u0);
            ACCM(a, u1);
            ACCM(a, u2);
            ACCM(a, u3);
        }
        for (; q + 32 < tot; q += 64) {
            int k0 = lst[q], k1 = lst[q + 32];
            uint4 u0 = xb4[(unsigned)((k0 << 4) | l16)];
            uint4 u1 = xb4[(unsigned)((k1 << 4) | l16)];
            ACCM(a, u0);
            ACCM(a, u1);
        }
        if (q < tot) {
            int k0 = lst[q];
            uint4 u0 = xb4[(unsigned)((k0 << 4) | l16)];
            ACCM(a, u0);
        }
    }

    // ---- cross-group reduction: shuffle within wave, then 8-wave LDS combine ----
    RED2(a0); RED2(a1); RED2(a2); RED2(a3); RED2(a4); RED2(a5); RED2(a6); RED2(a7);
    RED2(b0); RED2(b1); RED2(b2); RED2(b3); RED2(b4); RED2(b5); RED2(b6); RED2(b7);
    if (lane < 16) {
        red[wv][l16 * 8 + 0] = a0; red[wv][l16 * 8 + 1] = a1;
        red[wv][l16 * 8 + 2] = a2; red[wv][l16 * 8 + 3] = a3;
        red[wv][l16 * 8 + 4] = a4; red[wv][l16 * 8 + 5] = a5;
        red[wv][l16 * 8 + 6] = a6; red[wv][l16 * 8 + 7] = a7;
        red[wv][128 + l16 * 8 + 0] = b0; red[wv][128 + l16 * 8 + 1] = b1;
        red[wv][128 + l16 * 8 + 2] = b2; red[wv][128 + l16 * 8 + 3] = b3;
        red[wv][128 + l16 * 8 + 4] = b4; red[wv][128 + l16 * 8 + 5] = b5;
        red[wv][128 + l16 * 8 + 6] = b6; red[wv][128 + l16 * 8 + 7] = b7;
    }
    __syncthreads();
    if (tid < 256) {
        float s = 0.f;
#pragma unroll
        for (int w = 0; w < 8; ++w) s += red[w][tid];
        if (tid < 128) agg2[(size_t)i * C + tid] = s;
        else           agg1[(size_t)i * C + (tid - 128)] = s;
    }
}

// ---- fused epilogue: z1 = agg1@W1+b1, z2 = agg2@W2+b2, gate, combine ----
// 8 rows/block -> 1500 blocks (~5.9/CU) for occupancy; each thread 4 rows.
__global__ __launch_bounds__(256) void epilogue(const float* __restrict__ agg1,
                                                const float* __restrict__ agg2,
                                                const float* __restrict__ W1,
                                                const float* __restrict__ b1,
                                                const float* __restrict__ W2,
                                                const float* __restrict__ b2,
                                                const float* __restrict__ Wg,
                                                const float* __restrict__ bg,
                                                float* __restrict__ out) {
    __shared__ float sA[8][C];  // agg1 tile, then z1 tile
    __shared__ float sB[8][C];  // agg2 tile, then z2 tile
    const int r0 = blockIdx.x * 8;
    const int tid = threadIdx.x;
    const int c = tid & 127;
    const int rg = (tid >> 7) * 4;

    for (int idx = tid; idx < 8 * C; idx += 256) {
        int r = idx >> 7, k = idx & 127;
        sA[r][k] = agg1[(size_t)(r0 + r) * C + k];
        sB[r][k] = agg2[(size_t)(r0 + r) * C + k];
    }
    __syncthreads();

    float z1v[4], z2v[4];
#pragma unroll
    for (int r = 0; r < 4; ++r) { z1v[r] = 0.f; z2v[r] = 0.f; }
    for (int k = 0; k < C; k += 4) {
        float w10 = W1[(size_t)(k + 0) * C + c], w11 = W1[(size_t)(k + 1) * C + c];
        float w12 = W1[(size_t)(k + 2) * C + c], w13 = W1[(size_t)(k + 3) * C + c];
        float w20 = W2[(size_t)(k + 0) * C + c], w21 = W2[(size_t)(k + 1) * C + c];
        float w22 = W2[(size_t)(k + 2) * C + c], w23 = W2[(size_t)(k + 3) * C + c];
#pragma unroll
        for (int r = 0; r < 4; ++r) {
            float4 a = *(const float4*)&sA[rg + r][k];
            float4 b = *(const float4*)&sB[rg + r][k];
            z1v[r] += a.x * w10 + a.y * w11 + a.z * w12 + a.w * w13;
            z2v[r] += b.x * w20 + b.y * w21 + b.z * w22 + b.w * w23;
        }
    }
    const float b1v = b1[c], b2v = b2[c];
#pragma unroll
    for (int r = 0; r < 4; ++r) { z1v[r] += b1v; z2v[r] += b2v; }
    __syncthreads();
#pragma unroll
    for (int r = 0; r < 4; ++r) { sA[rg + r][c] = z1v[r]; sB[rg + r][c] = z2v[r]; }
    __syncthreads();

    float gacc[4];
#pragma unroll
    for (int r = 0; r < 4; ++r) gacc[r] = 0.f;
    for (int k = 0; k < C; k += 4) {
        float g10 = Wg[(size_t)(k + 0) * C + c], g11 = Wg[(size_t)(k + 1) * C + c];
        float g12 = Wg[(size_t)(k + 2) * C + c], g13 = Wg[(size_t)(k + 3) * C + c];
        float g20 = Wg[(size_t)(C + k + 0) * C + c], g21 = Wg[(size_t)(C + k + 1) * C + c];
        float g22 = Wg[(size_t)(C + k + 2) * C + c], g23 = Wg[(size_t)(C + k + 3) * C + c];
#pragma unroll
        for (int r = 0; r < 4; ++r) {
            float4 a = *(const float4*)&sA[rg + r][k];
            float4 b = *(const float4*)&sB[rg + r][k];
            gacc[r] += a.x * g10 + a.y * g11 + a.z * g12 + a.w * g13
                     + b.x * g20 + b.y * g21 + b.z * g22 + b.w * g23;
        }
    }
    const float bgv = bg[c];
#pragma unroll
    for (int r = 0; r < 4; ++r) {
        float g = 1.f / (1.f + expf(-(gacc[r] + bgv)));
        out[(size_t)(r0 + rg + r) * C + c] = g * z1v[r] + (1.f - g) * z2v[r];
    }
}

extern "C" void kernel_launch(void* const* d_in, const int* in_sizes, int n_in,
                              void* d_out, int out_size, void* d_ws, size_t ws_size,
                              hipStream_t stream) {
    const float* x  = (const float*)d_in[0];
    const int*   ei = (const int*)d_in[1];
    const float* W1 = (const float*)d_in[2];
    const float* b1 = (const float*)d_in[3];
    const float* W2 = (const float*)d_in[4];
    const float* b2 = (const float*)d_in[5];
    const float* Wg = (const float*)d_in[6];
    const float* bg = (const float*)d_in[7];
    float* out = (float*)d_out;

    char* ws = (char*)d_ws;
    size_t o = 0;
    auto alloc = [&](size_t bytes) { char* p = ws + o; o = (o + bytes + 255) & ~(size_t)255; return p; };
    int* col      = (int*)alloc((size_t)NEDGE * 4);
    int* deg      = (int*)alloc((size_t)N_NODES * 2 * 4);   // deg + cur contiguous
    int* cur      = deg + N_NODES;
    int* off      = (int*)alloc((size_t)(N_NODES + 1) * 4);
    unsigned* xb  = (unsigned*)alloc((size_t)N_NODES * C * 2);  // f16 x
    float* agg1   = (float*)alloc((size_t)N_NODES * C * 4);
    float* agg2   = (float*)alloc((size_t)N_NODES * C * 4);

    hipMemsetAsync(deg, 0, (size_t)N_NODES * 2 * 4, stream);

    prep<<<(N_NODES * C / 2 + 255) / 256, 256, 0, stream>>>(x, xb, ei, deg);
    scan_offsets<<<1, 1024, 0, stream>>>(deg, off);
    fill_csr<<<(NEDGE + 255) / 256, 256, 0, stream>>>(ei, off, cur, col);
    twohop_fused<<<N_NODES, 512, 0, stream>>>(off, col, xb, agg1, agg2);
    epilogue<<<N_NODES / 8, 256, 0, stream>>>(agg1, agg2, W1, b1, W2, b2, Wg, bg, out);
}

// Round 8
// 156.853 us; speedup vs baseline: 1.1584x; 1.1584x over previous
//
#include <hip/hip_runtime.h>
#include <hip/hip_fp16.h>
#include <math.h>

#define N_NODES 12000
#define C 128
#define NEDGE 192000
#define BW 384  // u32 words per LDS dedup bitset (12288 bits >= 12000)

// acc_lo += (float)f16_lo(u); acc_hi += (float)f16_hi(u)  -- one VOP3P each
__device__ __forceinline__ void fmix2(float& lo, float& hi, unsigned u, float one) {
    asm("v_fma_mix_f32 %0, %2, %3, %0 op_sel:[0,0,0] op_sel_hi:[1,0,0]\n\t"
        "v_fma_mix_f32 %1, %2, %3, %1 op_sel:[1,0,0] op_sel_hi:[1,0,0]"
        : "+v"(lo), "+v"(hi)
        : "v"(u), "v"(one));
}

#define ACCM(p, u)                                            \
    fmix2(p##0, p##1, u.x, one); fmix2(p##2, p##3, u.y, one); \
    fmix2(p##4, p##5, u.z, one); fmix2(p##6, p##7, u.w, one)

#define RED2(x) x += __shfl_xor(x, 16); x += __shfl_xor(x, 32)

// ---- fused: x (fp32) -> f16 packed pairs  +  out-degree histogram ----
__global__ void prep(const float* __restrict__ x, unsigned* __restrict__ xbu,
                     const int* __restrict__ ei, int* __restrict__ deg) {
    int g = blockIdx.x * blockDim.x + threadIdx.x;
    if (g < N_NODES * C / 2) {
        unsigned pa = __half_as_ushort(__float2half(x[2 * g]));
        unsigned pb = __half_as_ushort(__float2half(x[2 * g + 1]));
        xbu[g] = pa | (pb << 16);
    }
    if (g < NEDGE) atomicAdd(&deg[ei[g]], 1);
}

// ---- exclusive scan of degrees -> CSR offsets (single 1024-thread block) ----
__global__ __launch_bounds__(1024) void scan_offsets(const int* __restrict__ deg,
                                                     int* __restrict__ off) {
    __shared__ int wsum[16];
    const int t = threadIdx.x;
    const int lane = t & 63, wv = t >> 6;
    const int PER = 12;  // 1024*12 = 12288 >= 12000
    const int lo = t * PER;
    int local[PER];
    int sum = 0;
#pragma unroll
    for (int k = 0; k < PER; ++k) {
        int i = lo + k;
        int d = (i < N_NODES) ? deg[i] : 0;
        local[k] = sum;
        sum += d;
    }
    int p = sum;
    for (int d = 1; d < 64; d <<= 1) {
        int u = __shfl_up(p, d);
        if (lane >= d) p += u;
    }
    if (lane == 63) wsum[wv] = p;
    __syncthreads();
    int wbase = 0;
    for (int k = 0; k < wv; ++k) wbase += wsum[k];
    const int tbase = wbase + p - sum;
#pragma unroll
    for (int k = 0; k < PER; ++k) {
        int i = lo + k;
        if (i < N_NODES) off[i] = tbase + local[k];
    }
    if (t == 0) off[N_NODES] = NEDGE;
}

// ---- fill CSR columns (order within row irrelevant; duplicates kept) ----
__global__ void fill_csr(const int* __restrict__ ei, const int* __restrict__ off,
                         int* __restrict__ cur, int* __restrict__ col) {
    int e = blockIdx.x * blockDim.x + threadIdx.x;
    if (e >= NEDGE) return;
    int s = ei[e];
    int t = ei[NEDGE + e];
    int pos = atomicAdd(&cur[s], 1);
    col[off[s] + pos] = t;
}

// ---- fused: agg1 (f16 CSR gather) + flattened 2-hop union + list gather ----
__global__ __launch_bounds__(256) void twohop_fused(const int* __restrict__ off,
                                                    const int* __restrict__ col,
                                                    const unsigned* __restrict__ xb,
                                                    float* __restrict__ agg1,
                                                    float* __restrict__ agg2) {
    __shared__ unsigned acc[BW];          // 1.5 KB dedup bitset
    __shared__ int sjb[64];
    __shared__ int spos[64];
    __shared__ int stot;
    __shared__ int wtot[2];
    __shared__ unsigned short lst[4096];  // 8 KB; chunk cap = 128 words * 32 bits
    __shared__ float red[4][256];         // 4 KB
    const int i = blockIdx.x;
    const int tid = threadIdx.x;
    const int lane = tid & 63;
    const int wv = tid >> 6;
    const int grp = tid >> 4, l16 = tid & 15;
    const int rowbeg = off[i], rowend = off[i + 1];
    const uint4* xb4 = (const uint4*)xb;
    const float one = 1.0f;

    for (int w = tid; w < BW; w += 256) acc[w] = 0u;
    __syncthreads();  // acc ready for atomics

    // ---- 2-hop union, flattened per 64-neighbor chunk ----
    for (int base = rowbeg; base < rowend; base += 64) {
        int d = rowend - base;
        if (d > 64) d = 64;
        if (tid < 64) {
            int len = 0;
            if (tid < d) {
                int j = col[base + tid];
                int jb = off[j];
                len = off[j + 1] - jb;
                sjb[tid] = jb;
            }
            int p = len;
            for (int dd = 1; dd < 64; dd <<= 1) {
                int u = __shfl_up(p, dd);
                if (lane >= dd) p += u;
            }
            spos[tid] = p - len;  // exclusive
            if (tid == 63) stot = p;
        }
        __syncthreads();
        const int total = stot;
        for (int q = tid; q < total; q += 256) {
            int lo = 0, hi = d - 1;  // largest k with spos[k] <= q
            while (lo < hi) {
                int mid = (lo + hi + 1) >> 1;
                if (spos[mid] <= q) lo = mid; else hi = mid - 1;
            }
            int t = col[sjb[lo] + (q - spos[lo])];
            atomicOr(&acc[t >> 5], 1u << (t & 31));
        }
        __syncthreads();
    }
    if (tid == 0) acc[i >> 5] &= ~(1u << (i & 31));  // zero diagonal

    // ---- agg1: f16 counted gather over own row (multiplicity kept), 2x unrolled ----
    float b0 = 0, b1 = 0, b2 = 0, b3 = 0, b4 = 0, b5 = 0, b6 = 0, b7 = 0;
    {
        int idx = rowbeg + grp;
        for (; idx + 16 < rowend; idx += 32) {
            int k0 = col[idx], k1 = col[idx + 16];
            uint4 u0 = xb4[(unsigned)((k0 << 4) | l16)];
            uint4 u1 = xb4[(unsigned)((k1 << 4) | l16)];
            ACCM(b, u0);
            ACCM(b, u1);
        }
        if (idx < rowend) {
            int k0 = col[idx];
            uint4 u0 = xb4[(unsigned)((k0 << 4) | l16)];
            ACCM(b, u0);
        }
    }

    // ---- agg2: per-chunk enumerate (prefix-scan) + counted gather, 4x unrolled ----
    float a0 = 0, a1 = 0, a2 = 0, a3 = 0, a4 = 0, a5 = 0, a6 = 0, a7 = 0;
    for (int chunk = 0; chunk < 3; ++chunk) {
        __syncthreads();  // chunk 0: diag clear visible; others: lst consumed
        unsigned v = 0;
        int n = 0, p = 0;
        if (tid < 128) {
            v = acc[chunk * 128 + tid];
            n = __popc(v);
            p = n;
            for (int dd = 1; dd < 64; dd <<= 1) {
                int u = __shfl_up(p, dd);
                if (lane >= dd) p += u;
            }
            if (lane == 63) wtot[wv] = p;
        }
        __syncthreads();
        if (tid < 128) {
            int o = ((wv == 1) ? wtot[0] : 0) + p - n;
            int wbase = (chunk * 128 + tid) << 5;
            while (v) {
                int b = __ffs(v) - 1;
                v &= v - 1;
                lst[o++] = (unsigned short)(wbase + b);
            }
        }
        __syncthreads();
        const int total = wtot[0] + wtot[1];
        int q = grp;
        for (; q + 48 < total; q += 64) {
            int k0 = lst[q], k1 = lst[q + 16], k2 = lst[q + 32], k3 = lst[q + 48];
            uint4 u0 = xb4[(unsigned)((k0 << 4) | l16)];
            uint4 u1 = xb4[(unsigned)((k1 << 4) | l16)];
            uint4 u2 = xb4[(unsigned)((k2 << 4) | l16)];
            uint4 u3 = xb4[(unsigned)((k3 << 4) | l16)];
            ACCM(a, u0);
            ACCM(a, u1);
            ACCM(a, u2);
            ACCM(a, u3);
        }
        for (; q + 16 < total; q += 32) {
            int k0 = lst[q], k1 = lst[q + 16];
            uint4 u0 = xb4[(unsigned)((k0 << 4) | l16)];
            uint4 u1 = xb4[(unsigned)((k1 << 4) | l16)];
            ACCM(a, u0);
            ACCM(a, u1);
        }
        if (q < total) {
            int k0 = lst[q];
            uint4 u0 = xb4[(unsigned)((k0 << 4) | l16)];
            ACCM(a, u0);
        }
    }

    // ---- cross-group reduction: shuffle within wave, then 4-wave LDS combine ----
    RED2(a0); RED2(a1); RED2(a2); RED2(a3); RED2(a4); RED2(a5); RED2(a6); RED2(a7);
    RED2(b0); RED2(b1); RED2(b2); RED2(b3); RED2(b4); RED2(b5); RED2(b6); RED2(b7);
    __syncthreads();
    if (lane < 16) {
        red[wv][l16 * 8 + 0] = a0; red[wv][l16 * 8 + 1] = a1;
        red[wv][l16 * 8 + 2] = a2; red[wv][l16 * 8 + 3] = a3;
        red[wv][l16 * 8 + 4] = a4; red[wv][l16 * 8 + 5] = a5;
        red[wv][l16 * 8 + 6] = a6; red[wv][l16 * 8 + 7] = a7;
        red[wv][128 + l16 * 8 + 0] = b0; red[wv][128 + l16 * 8 + 1] = b1;
        red[wv][128 + l16 * 8 + 2] = b2; red[wv][128 + l16 * 8 + 3] = b3;
        red[wv][128 + l16 * 8 + 4] = b4; red[wv][128 + l16 * 8 + 5] = b5;
        red[wv][128 + l16 * 8 + 6] = b6; red[wv][128 + l16 * 8 + 7] = b7;
    }
    __syncthreads();
    float s = red[0][tid] + red[1][tid] + red[2][tid] + red[3][tid];
    if (tid < 128) agg2[(size_t)i * C + tid] = s;
    else           agg1[(size_t)i * C + (tid - 128)] = s;
}

// ---- fused epilogue: z1 = agg1@W1+b1, z2 = agg2@W2+b2, gate, combine ----
// 8 rows/block -> 1500 blocks (~5.9/CU) for occupancy; each thread 4 rows.
__global__ __launch_bounds__(256) void epilogue(const float* __restrict__ agg1,
                                                const float* __restrict__ agg2,
                                                const float* __restrict__ W1,
                                                const float* __restrict__ b1,
                                                const float* __restrict__ W2,
                                                const float* __restrict__ b2,
                                                const float* __restrict__ Wg,
                                                const float* __restrict__ bg,
                                                float* __restrict__ out) {
    __shared__ float sA[8][C];  // agg1 tile, then z1 tile
    __shared__ float sB[8][C];  // agg2 tile, then z2 tile
    const int r0 = blockIdx.x * 8;
    const int tid = threadIdx.x;
    const int c = tid & 127;
    const int rg = (tid >> 7) * 4;

    for (int idx = tid; idx < 8 * C; idx += 256) {
        int r = idx >> 7, k = idx & 127;
        sA[r][k] = agg1[(size_t)(r0 + r) * C + k];
        sB[r][k] = agg2[(size_t)(r0 + r) * C + k];
    }
    __syncthreads();

    float z1v[4], z2v[4];
#pragma unroll
    for (int r = 0; r < 4; ++r) { z1v[r] = 0.f; z2v[r] = 0.f; }
    for (int k = 0; k < C; k += 4) {
        float w10 = W1[(size_t)(k + 0) * C + c], w11 = W1[(size_t)(k + 1) * C + c];
        float w12 = W1[(size_t)(k + 2) * C + c], w13 = W1[(size_t)(k + 3) * C + c];
        float w20 = W2[(size_t)(k + 0) * C + c], w21 = W2[(size_t)(k + 1) * C + c];
        float w22 = W2[(size_t)(k + 2) * C + c], w23 = W2[(size_t)(k + 3) * C + c];
#pragma unroll
        for (int r = 0; r < 4; ++r) {
            float4 a = *(const float4*)&sA[rg + r][k];
            float4 b = *(const float4*)&sB[rg + r][k];
            z1v[r] += a.x * w10 + a.y * w11 + a.z * w12 + a.w * w13;
            z2v[r] += b.x * w20 + b.y * w21 + b.z * w22 + b.w * w23;
        }
    }
    const float b1v = b1[c], b2v = b2[c];
#pragma unroll
    for (int r = 0; r < 4; ++r) { z1v[r] += b1v; z2v[r] += b2v; }
    __syncthreads();
#pragma unroll
    for (int r = 0; r < 4; ++r) { sA[rg + r][c] = z1v[r]; sB[rg + r][c] = z2v[r]; }
    __syncthreads();

    float gacc[4];
#pragma unroll
    for (int r = 0; r < 4; ++r) gacc[r] = 0.f;
    for (int k = 0; k < C; k += 4) {
        float g10 = Wg[(size_t)(k + 0) * C + c], g11 = Wg[(size_t)(k + 1) * C + c];
        float g12 = Wg[(size_t)(k + 2) * C + c], g13 = Wg[(size_t)(k + 3) * C + c];
        float g20 = Wg[(size_t)(C + k + 0) * C + c], g21 = Wg[(size_t)(C + k + 1) * C + c];
        float g22 = Wg[(size_t)(C + k + 2) * C + c], g23 = Wg[(size_t)(C + k + 3) * C + c];
#pragma unroll
        for (int r = 0; r < 4; ++r) {
            float4 a = *(const float4*)&sA[rg + r][k];
            float4 b = *(const float4*)&sB[rg + r][k];
            gacc[r] += a.x * g10 + a.y * g11 + a.z * g12 + a.w * g13
                     + b.x * g20 + b.y * g21 + b.z * g22 + b.w * g23;
        }
    }
    const float bgv = bg[c];
#pragma unroll
    for (int r = 0; r < 4; ++r) {
        float g = 1.f / (1.f + expf(-(gacc[r] + bgv)));
        out[(size_t)(r0 + rg + r) * C + c] = g * z1v[r] + (1.f - g) * z2v[r];
    }
}

extern "C" void kernel_launch(void* const* d_in, const int* in_sizes, int n_in,
                              void* d_out, int out_size, void* d_ws, size_t ws_size,
                              hipStream_t stream) {
    const float* x  = (const float*)d_in[0];
    const int*   ei = (const int*)d_in[1];
    const float* W1 = (const float*)d_in[2];
    const float* b1 = (const float*)d_in[3];
    const float* W2 = (const float*)d_in[4];
    const float* b2 = (const float*)d_in[5];
    const float* Wg = (const float*)d_in[6];
    const float* bg = (const float*)d_in[7];
    float* out = (float*)d_out;

    char* ws = (char*)d_ws;
    size_t o = 0;
    auto alloc = [&](size_t bytes) { char* p = ws + o; o = (o + bytes + 255) & ~(size_t)255; return p; };
    int* col      = (int*)alloc((size_t)NEDGE * 4);
    int* deg      = (int*)alloc((size_t)N_NODES * 2 * 4);   // deg + cur contiguous
    int* cur      = deg + N_NODES;
    int* off      = (int*)alloc((size_t)(N_NODES + 1) * 4);
    unsigned* xb  = (unsigned*)alloc((size_t)N_NODES * C * 2);  // f16 x
    float* agg1   = (float*)alloc((size_t)N_NODES * C * 4);
    float* agg2   = (float*)alloc((size_t)N_NODES * C * 4);

    hipMemsetAsync(deg, 0, (size_t)N_NODES * 2 * 4, stream);

    prep<<<(N_NODES * C / 2 + 255) / 256, 256, 0, stream>>>(x, xb, ei, deg);
    scan_offsets<<<1, 1024, 0, stream>>>(deg, off);
    fill_csr<<<(NEDGE + 255) / 256, 256, 0, stream>>>(ei, off, cur, col);
    twohop_fused<<<N_NODES, 256, 0, stream>>>(off, col, xb, agg1, agg2);
    epilogue<<<N_NODES / 8, 256, 0, stream>>>(agg1, agg2, W1, b1, W2, b2, Wg, bg, out);
}